// Round 1
// baseline (846.823 us; speedup 1.0000x reference)
//
#include <hip/hip_runtime.h>
#include <hip/hip_bf16.h>
#include <math.h>

// Problem constants
#define NIMG 16
#define MPI  8          // masks per image
#define NPAIR 128       // NIMG*MPI
#define RTOK 4          // region tokens
#define HW_  336
#define NN_  24
#define P_   576        // 24*24
#define C_   1024
#define CH_  4096
#define NTOK 64         // NIMG*RTOK
#define TAPS 28
#define TAPS_P 29       // padded LDS stride (coprime with 32 banks)

__device__ __forceinline__ int wstart(int o){ int s = 14*o - 7; return s < 0 ? 0 : s; }

// ---------------- Kernel 1: mask resize (bilinear antialias) + threshold + compact ----------------
__global__ __launch_bounds__(256) void k_mask(const float* __restrict__ masks,
                                              unsigned short* __restrict__ actIdx,
                                              int* __restrict__ cnt) {
  int pair = blockIdx.x;
  const float* gm = masks + (size_t)pair * (HW_*HW_);
  __shared__ float wW[NN_][TAPS_P];
  __shared__ float T[HW_][NN_];
  __shared__ int lcnt;
  int tid = threadIdx.x;

  if (tid < NN_) {
    int o = tid;
    int st = wstart(o);
    float s_o = 14.0f*(float)o + 6.5f;
    float tmp[TAPS];
    float sum = 0.f;
    for (int t = 0; t < TAPS; t++) {
      int p = st + t;
      float w = 0.f;
      if (p < HW_) {
        float x = fabsf((float)p - s_o) * (1.0f/14.0f);
        w = fmaxf(0.f, 1.f - x);
      }
      tmp[t] = w; sum += w;
    }
    float inv = 1.0f / sum;   // JAX normalizes weights per output
    for (int t = 0; t < TAPS; t++) wW[o][t] = tmp[t]*inv;
  }
  if (tid == 0) lcnt = 0;
  __syncthreads();

  // pass A: resize along width -> T[r][oc]
  for (int idx = tid; idx < HW_*NN_; idx += 256) {
    int r = idx / NN_, oc = idx % NN_;
    int st = wstart(oc);
    const float* row = gm + r*HW_;
    float s = 0.f;
    #pragma unroll
    for (int t = 0; t < TAPS; t++) {
      int p = st + t;
      if (p < HW_) s += wW[oc][t] * row[p];
    }
    T[r][oc] = s;
  }
  __syncthreads();

  // pass B: resize along height, threshold, compact active pixel indices
  for (int idx = tid; idx < NN_*NN_; idx += 256) {
    int oh = idx / NN_, ow = idx % NN_;
    int st = wstart(oh);
    float s = 0.f;
    #pragma unroll
    for (int t = 0; t < TAPS; t++) {
      int r = st + t;
      if (r < HW_) s += wW[oh][t] * T[r][ow];
    }
    if (s > 0.f) {
      int pos = atomicAdd(&lcnt, 1);
      actIdx[(size_t)pair*P_ + pos] = (unsigned short)idx;
    }
  }
  __syncthreads();
  if (tid == 0) cnt[pair] = lcnt;
}

// ---------------- Kernel 2: masked pooling (partials over 4 pixel slices) ----------------
__global__ __launch_bounds__(256) void k_pool(const float* __restrict__ feats,
                                              const unsigned short* __restrict__ actIdx,
                                              const int* __restrict__ cnt,
                                              float* __restrict__ poolPart) {
  int slice = blockIdx.x & 3;
  int pair  = blockIdx.x >> 2;
  int n  = cnt[pair];
  int lo = (n * slice) >> 2;
  int hi = (n * (slice+1)) >> 2;
  int tid = threadIdx.x;
  const unsigned short* ai = actIdx + (size_t)pair*P_;
  const float* fb = feats + (size_t)pair * P_ * C_ + 4*tid;
  float4 acc = make_float4(0.f, 0.f, 0.f, 0.f);
  for (int i = lo; i < hi; i++) {
    const float4 v = *(const float4*)(fb + (size_t)ai[i]*C_);
    acc.x += v.x; acc.y += v.y; acc.z += v.z; acc.w += v.w;
  }
  *(float4*)(poolPart + ((size_t)slice*NPAIR + pair)*C_ + 4*tid) = acc;
}

// ---------------- Kernel 3: per-image token merge -> tokT [C_][64] ----------------
__global__ __launch_bounds__(256) void k_merge(const float* __restrict__ poolPart,
                                               const int* __restrict__ cnt,
                                               float* __restrict__ tokT) {
  int img = blockIdx.x;
  int tid = threadIdx.x;
  __shared__ float pool[MPI][C_];
  __shared__ float nrm[MPI][C_];
  __shared__ float red[256];
  __shared__ float norms[MPI];
  __shared__ float sims[MPI-1];
  __shared__ int seg[MPI];

  for (int idx = tid; idx < MPI*C_; idx += 256) {
    int m_ = idx >> 10, c = idx & (C_-1);
    int pair = img*MPI + m_;
    float s = poolPart[((size_t)0*NPAIR + pair)*C_ + c]
            + poolPart[((size_t)1*NPAIR + pair)*C_ + c]
            + poolPart[((size_t)2*NPAIR + pair)*C_ + c]
            + poolPart[((size_t)3*NPAIR + pair)*C_ + c];
    pool[m_][c] = s / ((float)cnt[pair] + 1e-8f);
  }
  __syncthreads();

  // norms
  for (int m_ = 0; m_ < MPI; m_++) {
    float s = 0.f;
    for (int c = tid; c < C_; c += 256) { float v = pool[m_][c]; s += v*v; }
    red[tid] = s; __syncthreads();
    for (int st = 128; st > 0; st >>= 1) { if (tid < st) red[tid] += red[tid+st]; __syncthreads(); }
    if (tid == 0) norms[m_] = fmaxf(sqrtf(red[0]), 1e-12f);
    __syncthreads();
  }
  for (int idx = tid; idx < MPI*C_; idx += 256) {
    int m_ = idx >> 10, c = idx & (C_-1);
    nrm[m_][c] = pool[m_][c] / norms[m_];
  }
  __syncthreads();

  // consecutive cosine sims
  for (int i = 0; i < MPI-1; i++) {
    float s = 0.f;
    for (int c = tid; c < C_; c += 256) s += nrm[i][c]*nrm[i+1][c];
    red[tid] = s; __syncthreads();
    for (int st = 128; st > 0; st >>= 1) { if (tid < st) red[tid] += red[tid+st]; __syncthreads(); }
    if (tid == 0) sims[i] = red[0];
    __syncthreads();
  }

  if (tid == 0) {
    float v[MPI-1];
    for (int i = 0; i < MPI-1; i++) v[i] = sims[i];
    for (int i = 1; i < MPI-1; i++) {            // insertion sort desc
      float key = v[i]; int j = i-1;
      while (j >= 0 && v[j] < key) { v[j+1] = v[j]; j--; }
      v[j+1] = key;
    }
    float kth = v[RTOK-1];                        // 4th largest of 7
    int s = 0; seg[0] = 0;
    for (int i = 1; i < MPI; i++) { if (sims[i-1] < kth) s++; seg[i] = s; }
  }
  __syncthreads();

  // segment means -> transposed tokens tokT[c][img*4 + r]
  for (int idx = tid; idx < RTOK*C_; idx += 256) {
    int r = idx >> 10, c = idx & (C_-1);
    float s = 0.f; int k = 0;
    #pragma unroll
    for (int m_ = 0; m_ < MPI; m_++) {
      if (seg[m_] == r) { s += pool[m_][c]; k++; }
    }
    tokT[(size_t)c*NTOK + img*RTOK + r] = s / fmaxf((float)k, 1.0f);
  }
}

// ---------------- Generic skinny GEMM: part[ks][m][j] = sum_{k in slice} AT[k][m]*W[k][j] ----------------
__global__ __launch_bounds__(256) void k_gemm(const float* __restrict__ AT,  // [K][64]
                                              const float* __restrict__ W,   // [K][N]
                                              float* __restrict__ part,      // [S][64][N]
                                              int N, int KS) {
  int cb = blockIdx.x;                   // column block (256 cols)
  int ks = blockIdx.y;                   // k slice
  int wv = threadIdx.x >> 6, ln = threadIdx.x & 63;
  int j0 = __builtin_amdgcn_readfirstlane(cb*256 + wv*64);
  int k0 = ks*KS;
  float acc[64];
  #pragma unroll
  for (int j = 0; j < 64; j++) acc[j] = 0.f;

  const float* at = AT + (size_t)k0*NTOK + ln;
  const float* wp = W + (size_t)k0*N + j0;
  for (int k = 0; k < KS; k++) {
    float a = at[k*NTOK];                       // coalesced 256B/wave
    const float* wr = wp + (size_t)k*N;         // wave-uniform row
    #pragma unroll
    for (int j = 0; j < 64; j++) acc[j] = fmaf(wr[j], a, acc[j]);
  }
  float* o = part + ((size_t)ks*NTOK + ln)*N + j0;
  #pragma unroll
  for (int j = 0; j < 64; j++) o[j] = acc[j];
}

// ---------------- reduce1: sum 4 k-slices + b1, exact GELU, write hT [CH_][64] ----------------
__global__ __launch_bounds__(256) void k_reduce1(const float* __restrict__ part, // [4][64][CH_]
                                                 const float* __restrict__ b1,
                                                 float* __restrict__ hT) {
  __shared__ float tile[64][65];
  int j0 = blockIdx.x * 64;
  int tid = threadIdx.x;
  for (int i = tid; i < 64*64; i += 256) {
    int m = i >> 6, jj = i & 63;
    float s = 0.f;
    #pragma unroll
    for (int ss = 0; ss < 4; ss++) s += part[((size_t)ss*NTOK + m)*CH_ + j0 + jj];
    s += b1[j0 + jj];
    float g = 0.5f * s * (1.0f + erff(s * 0.70710678118654752f));
    tile[jj][m] = g;
  }
  __syncthreads();
  for (int i = tid; i < 64*64; i += 256) {
    int jj = i >> 6, m = i & 63;
    hT[(size_t)(j0 + jj)*NTOK + m] = tile[jj][m];
  }
}

// ---------------- reduce2: sum 16 k-slices + b2 -> d_out [64][CH_] ----------------
__global__ __launch_bounds__(256) void k_reduce2(const float* __restrict__ part, // [16][64][CH_]
                                                 const float* __restrict__ b2,
                                                 float* __restrict__ out) {
  int idx = blockIdx.x*256 + threadIdx.x;   // over 64*4096
  float s = 0.f;
  #pragma unroll
  for (int ss = 0; ss < 16; ss++) s += part[(size_t)ss*NTOK*CH_ + idx];
  out[idx] = s + b2[idx & (CH_-1)];
}

extern "C" void kernel_launch(void* const* d_in, const int* in_sizes, int n_in,
                              void* d_out, int out_size, void* d_ws, size_t ws_size,
                              hipStream_t stream) {
  (void)in_sizes; (void)n_in; (void)out_size; (void)ws_size;
  const float* feats = (const float*)d_in[0];
  const float* masks = (const float*)d_in[1];
  const float* W1    = (const float*)d_in[2];
  const float* b1    = (const float*)d_in[3];
  const float* W2    = (const float*)d_in[4];
  const float* b2    = (const float*)d_in[5];
  float* out = (float*)d_out;
  char* ws = (char*)d_ws;

  // workspace layout (bytes)
  unsigned short* actIdx = (unsigned short*)(ws + 0);            // 128*576*2      = 147456
  int*   cnt      = (int*)  (ws + 147456);                       // 128*4          = 512
  float* poolPart = (float*)(ws + 148224);                       // 4*128*1024*4   = 2097152
  float* tokT     = (float*)(ws + 148224 + 2097152);             // 1024*64*4      = 262144
  float* g1part   = (float*)(ws + 2507520);                      // 4*64*4096*4    = 4194304
  float* hT       = (float*)(ws + 6701824);                      // 4096*64*4      = 1048576
  float* g2part   = (float*)(ws + 7750400);                      // 16*64*4096*4   = 16777216
  // total ~24.5 MB

  k_mask <<<NPAIR, 256, 0, stream>>>(masks, actIdx, cnt);
  k_pool <<<NPAIR*4, 256, 0, stream>>>(feats, actIdx, cnt, poolPart);
  k_merge<<<NIMG, 256, 0, stream>>>(poolPart, cnt, tokT);
  // GEMM1: [64,1024] @ [1024,4096], 4 k-slices of 256
  k_gemm <<<dim3(CH_/256, 4), 256, 0, stream>>>(tokT, W1, g1part, CH_, 256);
  k_reduce1<<<CH_/64, 256, 0, stream>>>(g1part, b1, hT);
  // GEMM2: [64,4096] @ [4096,4096], 16 k-slices of 256
  k_gemm <<<dim3(CH_/256, 16), 256, 0, stream>>>(hT, W2, g2part, CH_, 256);
  k_reduce2<<<(NTOK*CH_)/256, 256, 0, stream>>>(g2part, b2, out);
}

// Round 3
// 740.534 us; speedup vs baseline: 1.1435x; 1.1435x over previous
//
#include <hip/hip_runtime.h>
#include <hip/hip_bf16.h>
#include <math.h>

// Problem constants
#define NIMG 16
#define MPI  8          // masks per image
#define NPAIR 128       // NIMG*MPI
#define RTOK 4          // region tokens
#define HW_  336
#define NN_  24
#define P_   576        // 24*24
#define C_   1024
#define CH_  4096
#define NTOK 64         // NIMG*RTOK
#define TAPS 28
#define TAPS_P 29
#define PSLICE 8        // k_pool pixel slices
#define S1 8            // GEMM1 k-slices (KS=128)
#define S2 16           // GEMM2 k-slices (KS=256)

__device__ __forceinline__ int wstart(int o){ int s = 14*o - 7; return s < 0 ? 0 : s; }

// ---------------- Kernel 1: mask resize (triangle antialias) + threshold + compact ----------------
__global__ __launch_bounds__(256) void k_mask(const float* __restrict__ masks,
                                              unsigned short* __restrict__ actIdx,
                                              int* __restrict__ cnt) {
  int pair = blockIdx.x;
  const float* gm = masks + (size_t)pair * (HW_*HW_);
  __shared__ float wW[NN_][TAPS_P];
  __shared__ float T[HW_][NN_];
  __shared__ int lcnt;
  int tid = threadIdx.x;

  if (tid < NN_) {
    int o = tid;
    int st = wstart(o);
    float s_o = 14.0f*(float)o + 6.5f;
    float tmp[TAPS];
    float sum = 0.f;
    for (int t = 0; t < TAPS; t++) {
      int p = st + t;
      float w = 0.f;
      if (p < HW_) {
        float x = fabsf((float)p - s_o) * (1.0f/14.0f);
        w = fmaxf(0.f, 1.f - x);
      }
      tmp[t] = w; sum += w;
    }
    float inv = 1.0f / sum;   // JAX normalizes weights per output
    for (int t = 0; t < TAPS; t++) wW[o][t] = tmp[t]*inv;
  }
  if (tid == 0) lcnt = 0;
  __syncthreads();

  // pass A: resize along width -> T[r][oc]
  for (int idx = tid; idx < HW_*NN_; idx += 256) {
    int r = idx / NN_, oc = idx % NN_;
    int st = wstart(oc);
    const float* row = gm + r*HW_;
    float s = 0.f;
    #pragma unroll
    for (int t = 0; t < TAPS; t++) {
      int p = st + t;
      if (p < HW_) s += wW[oc][t] * row[p];
    }
    T[r][oc] = s;
  }
  __syncthreads();

  // pass B: resize along height, threshold, compact active pixel indices
  for (int idx = tid; idx < NN_*NN_; idx += 256) {
    int oh = idx / NN_, ow = idx % NN_;
    int st = wstart(oh);
    float s = 0.f;
    #pragma unroll
    for (int t = 0; t < TAPS; t++) {
      int r = st + t;
      if (r < HW_) s += wW[oh][t] * T[r][ow];
    }
    if (s > 0.f) {
      int pos = atomicAdd(&lcnt, 1);
      actIdx[(size_t)pair*P_ + pos] = (unsigned short)idx;
    }
  }
  __syncthreads();
  if (tid == 0) cnt[pair] = lcnt;
}

// ---------------- Kernel 2: masked pooling (partials over PSLICE pixel slices) ----------------
__global__ __launch_bounds__(256) void k_pool(const float* __restrict__ feats,
                                              const unsigned short* __restrict__ actIdx,
                                              const int* __restrict__ cnt,
                                              float* __restrict__ poolPart) {
  int slice = blockIdx.x & (PSLICE-1);
  int pair  = blockIdx.x / PSLICE;
  int n  = cnt[pair];
  int lo = (n * slice) / PSLICE;
  int hi = (n * (slice+1)) / PSLICE;
  int tid = threadIdx.x;
  const unsigned short* ai = actIdx + (size_t)pair*P_;
  const float* fb = feats + (size_t)pair * P_ * C_ + 4*tid;
  float4 acc = make_float4(0.f, 0.f, 0.f, 0.f);
  for (int i = lo; i < hi; i++) {
    const float4 v = *(const float4*)(fb + (size_t)ai[i]*C_);
    acc.x += v.x; acc.y += v.y; acc.z += v.z; acc.w += v.w;
  }
  *(float4*)(poolPart + ((size_t)slice*NPAIR + pair)*C_ + 4*tid) = acc;
}

// ---------------- Kernel 3: per-image token merge -> tokT [C_][64] ----------------
__global__ __launch_bounds__(256) void k_merge(const float* __restrict__ poolPart,
                                               const int* __restrict__ cnt,
                                               float* __restrict__ tokT) {
  int img = blockIdx.x;
  int tid = threadIdx.x;
  int wv = tid >> 6, ln = tid & 63;
  __shared__ float pool[MPI][C_];
  __shared__ float nrm[MPI][C_];
  __shared__ float norms[MPI];
  __shared__ float sims[MPI];
  __shared__ int seg[MPI];

  for (int idx = tid; idx < MPI*C_; idx += 256) {
    int m_ = idx >> 10, c = idx & (C_-1);
    int pair = img*MPI + m_;
    float s = 0.f;
    #pragma unroll
    for (int sl = 0; sl < PSLICE; sl++)
      s += poolPart[((size_t)sl*NPAIR + pair)*C_ + c];
    pool[m_][c] = s / ((float)cnt[pair] + 1e-8f);
  }
  __syncthreads();

  // norms: wave wv handles m = 2*wv, 2*wv+1 (wave-parallel shfl reduce)
  for (int h = 0; h < 2; h++) {
    int m_ = wv*2 + h;
    float s = 0.f;
    for (int c = ln; c < C_; c += 64) { float v = pool[m_][c]; s += v*v; }
    for (int o = 32; o > 0; o >>= 1) s += __shfl_xor(s, o);
    if (ln == 0) norms[m_] = fmaxf(sqrtf(s), 1e-12f);
  }
  __syncthreads();

  for (int idx = tid; idx < MPI*C_; idx += 256) {
    int m_ = idx >> 10, c = idx & (C_-1);
    nrm[m_][c] = pool[m_][c] / norms[m_];
  }
  __syncthreads();

  // consecutive cosine sims: wave wv handles i = wv and wv+4
  for (int h = 0; h < 2; h++) {
    int i = wv + h*4;
    if (i < MPI-1) {
      float s = 0.f;
      for (int c = ln; c < C_; c += 64) s += nrm[i][c]*nrm[i+1][c];
      for (int o = 32; o > 0; o >>= 1) s += __shfl_xor(s, o);
      if (ln == 0) sims[i] = s;
    }
  }
  __syncthreads();

  if (tid == 0) {
    float v[MPI-1];
    for (int i = 0; i < MPI-1; i++) v[i] = sims[i];
    for (int i = 1; i < MPI-1; i++) {            // insertion sort desc
      float key = v[i]; int j = i-1;
      while (j >= 0 && v[j] < key) { v[j+1] = v[j]; j--; }
      v[j+1] = key;
    }
    float kth = v[RTOK-1];                        // 4th largest of 7
    int s = 0; seg[0] = 0;
    for (int i = 1; i < MPI; i++) { if (sims[i-1] < kth) s++; seg[i] = s; }
  }
  __syncthreads();

  // segment means -> transposed tokens tokT[c][img*4 + r]
  for (int idx = tid; idx < RTOK*C_; idx += 256) {
    int r = idx >> 10, c = idx & (C_-1);
    float s = 0.f; int k = 0;
    #pragma unroll
    for (int m_ = 0; m_ < MPI; m_++) {
      if (seg[m_] == r) { s += pool[m_][c]; k++; }
    }
    tokT[(size_t)c*NTOK + img*RTOK + r] = s / fmaxf((float)k, 1.0f);
  }
}

// ---------------- Skinny GEMM: part[ks][m][j] = sum_{k in slice} AT[k][m]*W[k][j] ----------------
// 1 wave per block; wave covers 64 cols x all 64 rows. lane: mi=ln>>4 (16-row group),
// ji=ln&15 (4-col group). W loads: per-lane float4, coalesced (16 distinct addrs/wave).
// A loads: 4x float4, 4 distinct addrs/wave (16-lane broadcast), served by L1/L2.
#define FMA4(ACC,AV) ACC.x=fmaf(AV,w.x,ACC.x);ACC.y=fmaf(AV,w.y,ACC.y);ACC.z=fmaf(AV,w.z,ACC.z);ACC.w=fmaf(AV,w.w,ACC.w)
__global__ __launch_bounds__(64) void k_gemm(const float* __restrict__ AT,  // [K][64]
                                             const float* __restrict__ W,   // [K][N]
                                             float* __restrict__ part,      // [S][64][N]
                                             int N, int KS) {
  int ln = threadIdx.x;
  int mi = ln >> 4;                 // 0..3
  int ji = ln & 15;                 // 0..15
  int jc = blockIdx.x*64 + ji*4;    // this thread's 4 columns
  int k0 = blockIdx.y*KS;
  float4 acc[16];
  #pragma unroll
  for (int r = 0; r < 16; r++) acc[r] = make_float4(0.f,0.f,0.f,0.f);

  const float* ap = AT + (size_t)k0*NTOK + mi*16;
  const float* wp = W  + (size_t)k0*N + jc;
  for (int k = 0; k < KS; k++) {
    float4 w  = *(const float4*)(wp);
    float4 a0 = *(const float4*)(ap);
    float4 a1 = *(const float4*)(ap+4);
    float4 a2 = *(const float4*)(ap+8);
    float4 a3 = *(const float4*)(ap+12);
    wp += N; ap += NTOK;
    FMA4(acc[0], a0.x); FMA4(acc[1], a0.y); FMA4(acc[2], a0.z); FMA4(acc[3], a0.w);
    FMA4(acc[4], a1.x); FMA4(acc[5], a1.y); FMA4(acc[6], a1.z); FMA4(acc[7], a1.w);
    FMA4(acc[8], a2.x); FMA4(acc[9], a2.y); FMA4(acc[10],a2.z); FMA4(acc[11],a2.w);
    FMA4(acc[12],a3.x); FMA4(acc[13],a3.y); FMA4(acc[14],a3.z); FMA4(acc[15],a3.w);
  }
  #pragma unroll
  for (int q = 0; q < 4; q++)
    #pragma unroll
    for (int r = 0; r < 4; r++) {
      int row = mi*16 + q*4 + r;
      *(float4*)(part + ((size_t)blockIdx.y*NTOK + row)*N + jc) = acc[q*4+r];
    }
}

// ---------------- reduce1: sum S1 k-slices + b1, exact GELU, write hT [CH_][64] ----------------
__global__ __launch_bounds__(256) void k_reduce1(const float* __restrict__ part, // [S1][64][CH_]
                                                 const float* __restrict__ b1,
                                                 float* __restrict__ hT) {
  __shared__ float tile[64][65];
  int j0 = blockIdx.x * 64;
  int tid = threadIdx.x;
  for (int i = tid; i < 64*64; i += 256) {
    int m = i >> 6, jj = i & 63;
    float s = 0.f;
    #pragma unroll
    for (int ss = 0; ss < S1; ss++) s += part[((size_t)ss*NTOK + m)*CH_ + j0 + jj];
    s += b1[j0 + jj];
    float g = 0.5f * s * (1.0f + erff(s * 0.70710678118654752f));
    tile[jj][m] = g;
  }
  __syncthreads();
  for (int i = tid; i < 64*64; i += 256) {
    int jj = i >> 6, m = i & 63;
    hT[(size_t)(j0 + jj)*NTOK + m] = tile[jj][m];
  }
}

// ---------------- reduce2: sum S2 k-slices + b2 -> d_out [64][CH_] ----------------
__global__ __launch_bounds__(256) void k_reduce2(const float* __restrict__ part, // [S2][64][CH_]
                                                 const float* __restrict__ b2,
                                                 float* __restrict__ out) {
  int idx = blockIdx.x*256 + threadIdx.x;   // over 64*4096
  float s = 0.f;
  #pragma unroll
  for (int ss = 0; ss < S2; ss++) s += part[(size_t)ss*NTOK*CH_ + idx];
  out[idx] = s + b2[idx & (CH_-1)];
}

extern "C" void kernel_launch(void* const* d_in, const int* in_sizes, int n_in,
                              void* d_out, int out_size, void* d_ws, size_t ws_size,
                              hipStream_t stream) {
  (void)in_sizes; (void)n_in; (void)out_size; (void)ws_size;
  const float* feats = (const float*)d_in[0];
  const float* masks = (const float*)d_in[1];
  const float* W1    = (const float*)d_in[2];
  const float* b1    = (const float*)d_in[3];
  const float* W2    = (const float*)d_in[4];
  const float* b2    = (const float*)d_in[5];
  float* out = (float*)d_out;
  char* ws = (char*)d_ws;

  // workspace layout (bytes, all 16B-aligned)
  unsigned short* actIdx = (unsigned short*)(ws + 0);        // 128*576*2            = 147456
  int*   cnt      = (int*)  (ws + 147456);                   // 128*4                = 512
  float* poolPart = (float*)(ws + 147968);                   // 8*128*1024*4         = 4194304
  float* tokT     = (float*)(ws + 4342272);                  // 1024*64*4            = 262144
  float* g1part   = (float*)(ws + 4604416);                  // 8*64*4096*4          = 8388608
  float* hT       = (float*)(ws + 12993024);                 // 4096*64*4            = 1048576
  float* g2part   = (float*)(ws + 14041600);                 // 16*64*4096*4         = 16777216
  // total ~30.8 MB

  k_mask <<<NPAIR, 256, 0, stream>>>(masks, actIdx, cnt);
  k_pool <<<NPAIR*PSLICE, 256, 0, stream>>>(feats, actIdx, cnt, poolPart);
  k_merge<<<NIMG, 256, 0, stream>>>(poolPart, cnt, tokT);
  // GEMM1: [64,1024] @ [1024,4096], S1 k-slices of 128
  k_gemm <<<dim3(CH_/64, S1), 64, 0, stream>>>(tokT, W1, g1part, CH_, C_/S1);
  k_reduce1<<<CH_/64, 256, 0, stream>>>(g1part, b1, hT);
  // GEMM2: [64,4096] @ [4096,4096], S2 k-slices of 256
  k_gemm <<<dim3(CH_/64, S2), 64, 0, stream>>>(hT, W2, g2part, CH_, CH_/S2);
  k_reduce2<<<(NTOK*CH_)/256, 256, 0, stream>>>(g2part, b2, out);
}

// Round 5
// 666.329 us; speedup vs baseline: 1.2709x; 1.1114x over previous
//
#include <hip/hip_runtime.h>
#include <hip/hip_bf16.h>
#include <math.h>

// Problem constants
#define NIMG 16
#define MPI  8          // masks per image
#define NPAIR 128       // NIMG*MPI
#define RTOK 4          // region tokens
#define HW_  336
#define NN_  24
#define P_   576        // 24*24
#define C_   1024
#define CH_  4096
#define NTOK 64         // NIMG*RTOK
#define TAPS 28
#define PSLICE 8        // k_pool pixel slices
#define S1 16           // GEMM1 k-slices (KS=64)
#define S2 16           // GEMM2 k-slices (KS=256)

__device__ __forceinline__ int wstart(int o){ int s = 14*o - 7; return s < 0 ? 0 : s; }

// ---------------- Kernel 1a: resize along W (all pairs, grid-stride) -> Tg[pair][r][oc] ----------------
__global__ __launch_bounds__(256) void k_resizeW(const float* __restrict__ masks,
                                                 float* __restrict__ Tg) {
  int gsz = gridDim.x * 256;
  for (int idx = blockIdx.x*256 + threadIdx.x; idx < NPAIR*HW_*NN_; idx += gsz) {
    int oc = idx % NN_;
    int rowIdx = idx / NN_;              // pair*336 + r
    const float* row = masks + (size_t)rowIdx * HW_;
    int st = wstart(oc);
    float s_o = 14.0f*(float)oc + 6.5f;
    float wt[TAPS];
    float wsum = 0.f;
    #pragma unroll
    for (int t = 0; t < TAPS; t++) {
      int p = st + t;
      float w = (p < HW_) ? fmaxf(0.f, 1.f - fabsf((float)p - s_o)*(1.0f/14.0f)) : 0.f;
      wt[t] = w; wsum += w;
    }
    float inv = 1.0f / wsum;             // JAX normalizes weights per output
    float s = 0.f;
    #pragma unroll
    for (int t = 0; t < TAPS; t++) {
      int p = st + t; p = (p < HW_) ? p : (HW_-1);   // clamped idx, weight is 0 beyond
      s += (wt[t]*inv) * row[p];
    }
    Tg[idx] = s;
  }
}

// ---------------- Kernel 1b: resize along H + threshold + compact ----------------
__global__ __launch_bounds__(256) void k_resizeH(const float* __restrict__ Tg,
                                                 unsigned short* __restrict__ actIdx,
                                                 int* __restrict__ cnt) {
  int pair = blockIdx.x;
  int tid = threadIdx.x;
  __shared__ float T[HW_*NN_];   // 32 KB
  __shared__ int lcnt;
  const float4* src = (const float4*)(Tg + (size_t)pair*HW_*NN_);
  float4* dst = (float4*)T;
  for (int i = tid; i < HW_*NN_/4; i += 256) dst[i] = src[i];
  if (tid == 0) lcnt = 0;
  __syncthreads();

  for (int idx = tid; idx < P_; idx += 256) {
    int oh = idx / NN_, ow = idx % NN_;
    int st = wstart(oh);
    float s_o = 14.0f*(float)oh + 6.5f;
    float wt[TAPS];
    float wsum = 0.f;
    #pragma unroll
    for (int t = 0; t < TAPS; t++) {
      int r = st + t;
      float w = (r < HW_) ? fmaxf(0.f, 1.f - fabsf((float)r - s_o)*(1.0f/14.0f)) : 0.f;
      wt[t] = w; wsum += w;
    }
    float inv = 1.0f / wsum;
    float s = 0.f;
    #pragma unroll
    for (int t = 0; t < TAPS; t++) {
      int r = st + t; r = (r < HW_) ? r : (HW_-1);
      s += (wt[t]*inv) * T[r*NN_ + ow];
    }
    if (s > 0.f) {
      int pos = atomicAdd(&lcnt, 1);
      actIdx[(size_t)pair*P_ + pos] = (unsigned short)idx;
    }
  }
  __syncthreads();
  if (tid == 0) cnt[pair] = lcnt;
}

// ---------------- Kernel 2: masked pooling, 8-deep unrolled gathers ----------------
__global__ __launch_bounds__(256) void k_pool(const float* __restrict__ feats,
                                              const unsigned short* __restrict__ actIdx,
                                              const int* __restrict__ cnt,
                                              float* __restrict__ poolPart) {
  int slice = blockIdx.x & (PSLICE-1);
  int pair  = blockIdx.x / PSLICE;
  int n  = cnt[pair];
  int lo = (n * slice) / PSLICE;
  int hi = (n * (slice+1)) / PSLICE;
  int tid = threadIdx.x;
  const unsigned short* ai = actIdx + (size_t)pair*P_;
  const float* fb = feats + (size_t)pair * P_ * C_ + 4*tid;
  float4 acc = make_float4(0.f, 0.f, 0.f, 0.f);
  int i = lo;
  for (; i + 8 <= hi; i += 8) {
    int r0 = ai[i+0], r1 = ai[i+1], r2 = ai[i+2], r3 = ai[i+3];
    int r4 = ai[i+4], r5 = ai[i+5], r6 = ai[i+6], r7 = ai[i+7];
    float4 v0 = *(const float4*)(fb + (size_t)r0*C_);
    float4 v1 = *(const float4*)(fb + (size_t)r1*C_);
    float4 v2 = *(const float4*)(fb + (size_t)r2*C_);
    float4 v3 = *(const float4*)(fb + (size_t)r3*C_);
    float4 v4 = *(const float4*)(fb + (size_t)r4*C_);
    float4 v5 = *(const float4*)(fb + (size_t)r5*C_);
    float4 v6 = *(const float4*)(fb + (size_t)r6*C_);
    float4 v7 = *(const float4*)(fb + (size_t)r7*C_);
    acc.x += v0.x; acc.y += v0.y; acc.z += v0.z; acc.w += v0.w;
    acc.x += v1.x; acc.y += v1.y; acc.z += v1.z; acc.w += v1.w;
    acc.x += v2.x; acc.y += v2.y; acc.z += v2.z; acc.w += v2.w;
    acc.x += v3.x; acc.y += v3.y; acc.z += v3.z; acc.w += v3.w;
    acc.x += v4.x; acc.y += v4.y; acc.z += v4.z; acc.w += v4.w;
    acc.x += v5.x; acc.y += v5.y; acc.z += v5.z; acc.w += v5.w;
    acc.x += v6.x; acc.y += v6.y; acc.z += v6.z; acc.w += v6.w;
    acc.x += v7.x; acc.y += v7.y; acc.z += v7.z; acc.w += v7.w;
  }
  for (; i < hi; i++) {
    const float4 v = *(const float4*)(fb + (size_t)ai[i]*C_);
    acc.x += v.x; acc.y += v.y; acc.z += v.z; acc.w += v.w;
  }
  *(float4*)(poolPart + ((size_t)slice*NPAIR + pair)*C_ + 4*tid) = acc;
}

// ---------------- Kernel 3: per-image token merge -> tokT [C_][64] ----------------
__global__ __launch_bounds__(256) void k_merge(const float* __restrict__ poolPart,
                                               const int* __restrict__ cnt,
                                               float* __restrict__ tokT) {
  int img = blockIdx.x;
  int tid = threadIdx.x;
  int wv = tid >> 6, ln = tid & 63;
  __shared__ float pool[MPI][C_];
  __shared__ float nrm[MPI][C_];
  __shared__ float norms[MPI];
  __shared__ float sims[MPI];
  __shared__ int seg[MPI];

  // sum the PSLICE partials (vectorized, independent loads)
  for (int idx = tid; idx < MPI*C_/4; idx += 256) {
    int m_ = idx >> 8, q = idx & 255;      // q: float4 index within row
    int pair = img*MPI + m_;
    float4 s = make_float4(0.f,0.f,0.f,0.f);
    #pragma unroll
    for (int sl = 0; sl < PSLICE; sl++) {
      float4 v = *(const float4*)(poolPart + ((size_t)sl*NPAIR + pair)*C_ + q*4);
      s.x += v.x; s.y += v.y; s.z += v.z; s.w += v.w;
    }
    float inv = 1.0f / ((float)cnt[pair] + 1e-8f);
    pool[m_][q*4+0] = s.x * inv; pool[m_][q*4+1] = s.y * inv;
    pool[m_][q*4+2] = s.z * inv; pool[m_][q*4+3] = s.w * inv;
  }
  __syncthreads();

  // norms: wave wv handles m = 2*wv, 2*wv+1
  for (int h = 0; h < 2; h++) {
    int m_ = wv*2 + h;
    float s = 0.f;
    for (int c = ln; c < C_; c += 64) { float v = pool[m_][c]; s += v*v; }
    for (int o = 32; o > 0; o >>= 1) s += __shfl_xor(s, o);
    if (ln == 0) norms[m_] = fmaxf(sqrtf(s), 1e-12f);
  }
  __syncthreads();

  for (int idx = tid; idx < MPI*C_; idx += 256) {
    int m_ = idx >> 10, c = idx & (C_-1);
    nrm[m_][c] = pool[m_][c] / norms[m_];
  }
  __syncthreads();

  // consecutive cosine sims: wave wv handles i = wv and wv+4
  for (int h = 0; h < 2; h++) {
    int i = wv + h*4;
    if (i < MPI-1) {
      float s = 0.f;
      for (int c = ln; c < C_; c += 64) s += nrm[i][c]*nrm[i+1][c];
      for (int o = 32; o > 0; o >>= 1) s += __shfl_xor(s, o);
      if (ln == 0) sims[i] = s;
    }
  }
  __syncthreads();

  if (tid == 0) {
    float v[MPI-1];
    for (int i = 0; i < MPI-1; i++) v[i] = sims[i];
    for (int i = 1; i < MPI-1; i++) {            // insertion sort desc
      float key = v[i]; int j = i-1;
      while (j >= 0 && v[j] < key) { v[j+1] = v[j]; j--; }
      v[j+1] = key;
    }
    float kth = v[RTOK-1];                        // 4th largest of 7
    int s = 0; seg[0] = 0;
    for (int i = 1; i < MPI; i++) { if (sims[i-1] < kth) s++; seg[i] = s; }
  }
  __syncthreads();

  // segment means -> transposed tokens tokT[c][img*4 + r]
  for (int idx = tid; idx < RTOK*C_; idx += 256) {
    int r = idx >> 10, c = idx & (C_-1);
    float s = 0.f; int k = 0;
    #pragma unroll
    for (int m_ = 0; m_ < MPI; m_++) {
      if (seg[m_] == r) { s += pool[m_][c]; k++; }
    }
    tokT[(size_t)c*NTOK + img*RTOK + r] = s / fmaxf((float)k, 1.0f);
  }
}

// ---------------- Skinny GEMM with depth-8 W prefetch ----------------
// 1 wave per block; wave covers 64 cols x all 64 rows. lane: mi=ln>>4 (16-row group),
// ji=ln&15 (4-col group). W loads: per-lane float4, coalesced; 8 rows in flight.
#define FMA4(ACC,AV) ACC.x=fmaf(AV,w.x,ACC.x);ACC.y=fmaf(AV,w.y,ACC.y);ACC.z=fmaf(AV,w.z,ACC.z);ACC.w=fmaf(AV,w.w,ACC.w)
__global__ __launch_bounds__(64) void k_gemm(const float* __restrict__ AT,  // [K][64]
                                             const float* __restrict__ W,   // [K][N]
                                             float* __restrict__ part,      // [S][64][N]
                                             int N, int KS) {
  int ln = threadIdx.x;
  int mi = ln >> 4;                 // 0..3
  int ji = ln & 15;                 // 0..15
  int jc = blockIdx.x*64 + ji*4;    // this thread's 4 columns
  int k0 = blockIdx.y*KS;
  float4 acc[16];
  #pragma unroll
  for (int r = 0; r < 16; r++) acc[r] = make_float4(0.f,0.f,0.f,0.f);

  const float* ap    = AT + (size_t)k0*NTOK + mi*16;
  const float* wbase = W  + (size_t)k0*N + jc;
  const float* wp    = wbase;
  float4 wbuf[8];
  #pragma unroll
  for (int kk = 0; kk < 8; kk++) wbuf[kk] = *(const float4*)(wp + (size_t)kk*N);
  wp += 8*(size_t)N;

  for (int k8 = 0; k8 < KS; k8 += 8) {
    bool more = (k8 + 8) < KS;
    const float* pre = more ? wp : wbase;    // last chunk: dummy in-bounds prefetch
    #pragma unroll
    for (int kk = 0; kk < 8; kk++) {
      float4 a0 = *(const float4*)(ap);
      float4 a1 = *(const float4*)(ap+4);
      float4 a2 = *(const float4*)(ap+8);
      float4 a3 = *(const float4*)(ap+12);
      ap += NTOK;
      float4 w = wbuf[kk];
      FMA4(acc[0], a0.x); FMA4(acc[1], a0.y); FMA4(acc[2], a0.z); FMA4(acc[3], a0.w);
      FMA4(acc[4], a1.x); FMA4(acc[5], a1.y); FMA4(acc[6], a1.z); FMA4(acc[7], a1.w);
      FMA4(acc[8], a2.x); FMA4(acc[9], a2.y); FMA4(acc[10],a2.z); FMA4(acc[11],a2.w);
      FMA4(acc[12],a3.x); FMA4(acc[13],a3.y); FMA4(acc[14],a3.z); FMA4(acc[15],a3.w);
      wbuf[kk] = *(const float4*)(pre + (size_t)kk*N);   // prefetch next chunk
    }
    wp += 8*(size_t)N;
  }
  #pragma unroll
  for (int q = 0; q < 4; q++)
    #pragma unroll
    for (int r = 0; r < 4; r++) {
      int row = mi*16 + q*4 + r;
      *(float4*)(part + ((size_t)blockIdx.y*NTOK + row)*N + jc) = acc[q*4+r];
    }
}

// ---------------- reduce1: sum S1 k-slices + b1, exact GELU, write hT [CH_][64] ----------------
__global__ __launch_bounds__(256) void k_reduce1(const float* __restrict__ part, // [S1][64][CH_]
                                                 const float* __restrict__ b1,
                                                 float* __restrict__ hT) {
  __shared__ float tile[64][65];
  int j0 = blockIdx.x * 64;
  int tid = threadIdx.x;
  for (int i = tid; i < 64*64; i += 256) {
    int m = i >> 6, jj = i & 63;
    float s = 0.f;
    #pragma unroll
    for (int ss = 0; ss < S1; ss++) s += part[((size_t)ss*NTOK + m)*CH_ + j0 + jj];
    s += b1[j0 + jj];
    float g = 0.5f * s * (1.0f + erff(s * 0.70710678118654752f));
    tile[jj][m] = g;
  }
  __syncthreads();
  for (int i = tid; i < 64*64; i += 256) {
    int jj = i >> 6, m = i & 63;
    hT[(size_t)(j0 + jj)*NTOK + m] = tile[jj][m];
  }
}

// ---------------- reduce2: sum S2 k-slices + b2 -> d_out [64][CH_] ----------------
__global__ __launch_bounds__(256) void k_reduce2(const float* __restrict__ part, // [S2][64][CH_]
                                                 const float* __restrict__ b2,
                                                 float* __restrict__ out) {
  int idx = blockIdx.x*256 + threadIdx.x;   // over 64*4096
  float s = 0.f;
  #pragma unroll
  for (int ss = 0; ss < S2; ss++) s += part[(size_t)ss*NTOK*CH_ + idx];
  out[idx] = s + b2[idx & (CH_-1)];
}

extern "C" void kernel_launch(void* const* d_in, const int* in_sizes, int n_in,
                              void* d_out, int out_size, void* d_ws, size_t ws_size,
                              hipStream_t stream) {
  (void)in_sizes; (void)n_in; (void)out_size; (void)ws_size;
  const float* feats = (const float*)d_in[0];
  const float* masks = (const float*)d_in[1];
  const float* W1    = (const float*)d_in[2];
  const float* b1    = (const float*)d_in[3];
  const float* W2    = (const float*)d_in[4];
  const float* b2    = (const float*)d_in[5];
  float* out = (float*)d_out;
  char* ws = (char*)d_ws;

  // workspace layout (bytes, all 16B-aligned)
  unsigned short* actIdx = (unsigned short*)(ws + 0);        // 128*576*2      = 147456
  int*   cnt      = (int*)  (ws + 147456);                   // 128*4 (pad)    = 512
  float* Tg       = (float*)(ws + 147968);                   // 128*336*24*4   = 4128768
  float* poolPart = (float*)(ws + 4276736);                  // 8*128*1024*4   = 4194304
  float* tokT     = (float*)(ws + 8471040);                  // 1024*64*4      = 262144
  float* g1part   = (float*)(ws + 8733184);                  // 16*64*4096*4   = 16777216
  float* hT       = (float*)(ws + 25510400);                 // 4096*64*4      = 1048576
  float* g2part   = (float*)(ws + 26558976);                 // 16*64*4096*4   = 16777216
  // total ~43.3 MB

  k_resizeW<<<1024, 256, 0, stream>>>(masks, Tg);
  k_resizeH<<<NPAIR, 256, 0, stream>>>(Tg, actIdx, cnt);
  k_pool <<<NPAIR*PSLICE, 256, 0, stream>>>(feats, actIdx, cnt, poolPart);
  k_merge<<<NIMG, 256, 0, stream>>>(poolPart, cnt, tokT);
  // GEMM1: [64,1024] @ [1024,4096], S1 k-slices of 64
  k_gemm <<<dim3(CH_/64, S1), 64, 0, stream>>>(tokT, W1, g1part, CH_, C_/S1);
  k_reduce1<<<CH_/64, 256, 0, stream>>>(g1part, b1, hT);
  // GEMM2: [64,4096] @ [4096,4096], S2 k-slices of 256
  k_gemm <<<dim3(CH_/64, S2), 64, 0, stream>>>(hT, W2, g2part, CH_, CH_/S2);
  k_reduce2<<<(NTOK*CH_)/256, 256, 0, stream>>>(g2part, b2, out);
}

// Round 6
// 663.671 us; speedup vs baseline: 1.2760x; 1.0040x over previous
//
#include <hip/hip_runtime.h>
#include <hip/hip_bf16.h>
#include <math.h>

// Problem constants
#define NIMG 16
#define MPI  8          // masks per image
#define NPAIR 128       // NIMG*MPI
#define RTOK 4          // region tokens
#define HW_  336
#define NN_  24
#define P_   576        // 24*24
#define C_   1024
#define CH_  4096
#define NTOK 64         // NIMG*RTOK
#define TAPS 28
#define TAPS_P 29       // padded LDS stride
#define PSLICE 8        // k_pool pixel slices
#define S1 16           // GEMM1 k-slices (KS=64)
#define S2 16           // GEMM2 k-slices (KS=256)

__device__ __forceinline__ int wstart(int o){ int s = 14*o - 7; return s < 0 ? 0 : s; }

// ---------------- Kernel 1: fused mask resize (W then H), threshold, compact ----------------
// One pair per block, 512 threads. Triangle-filter weights (JAX bilinear+antialias,
// half-pixel centers, per-output normalized) precomputed once into LDS — the same
// 24x28 table serves both axes (336->24 in both).
__global__ __launch_bounds__(512) void k_mask(const float* __restrict__ masks,
                                              unsigned short* __restrict__ actIdx,
                                              int* __restrict__ cnt) {
  int pair = blockIdx.x;
  const float* gm = masks + (size_t)pair * (HW_*HW_);
  __shared__ float wW[NN_][TAPS_P];
  __shared__ float T[HW_*NN_];    // 32.25 KB
  __shared__ int lcnt;
  int tid = threadIdx.x;

  if (tid < NN_) {
    int o = tid;
    int st = wstart(o);
    float s_o = 14.0f*(float)o + 6.5f;
    float tmp[TAPS];
    float sum = 0.f;
    #pragma unroll
    for (int t = 0; t < TAPS; t++) {
      int p = st + t;
      float w = (p < HW_) ? fmaxf(0.f, 1.f - fabsf((float)p - s_o)*(1.0f/14.0f)) : 0.f;
      tmp[t] = w; sum += w;
    }
    float inv = 1.0f / sum;       // JAX normalizes weights per output
    #pragma unroll
    for (int t = 0; t < TAPS; t++) wW[o][t] = tmp[t]*inv;
  }
  if (tid == 0) lcnt = 0;
  __syncthreads();

  // pass A: resize along width -> T[r*24 + oc]
  for (int idx = tid; idx < HW_*NN_; idx += 512) {
    int oc = idx % NN_;
    int r  = idx / NN_;
    const float* row = gm + (size_t)r*HW_;
    int st = wstart(oc);
    float s = 0.f;
    #pragma unroll
    for (int t = 0; t < TAPS; t++) {
      int p = st + t; p = (p < HW_) ? p : (HW_-1);  // weight is exactly 0 beyond edge
      s += wW[oc][t] * row[p];
    }
    T[idx] = s;
  }
  __syncthreads();

  // pass B: resize along height, threshold, compact active pixel indices
  for (int idx = tid; idx < P_; idx += 512) {
    int oh = idx / NN_, ow = idx % NN_;
    int st = wstart(oh);
    float s = 0.f;
    #pragma unroll
    for (int t = 0; t < TAPS; t++) {
      int r = st + t; r = (r < HW_) ? r : (HW_-1);
      s += wW[oh][t] * T[r*NN_ + ow];
    }
    if (s > 0.f) {
      int pos = atomicAdd(&lcnt, 1);
      actIdx[(size_t)pair*P_ + pos] = (unsigned short)idx;
    }
  }
  __syncthreads();
  if (tid == 0) cnt[pair] = lcnt;
}

// ---------------- Kernel 2: masked pooling, 8-deep unrolled gathers ----------------
__global__ __launch_bounds__(256) void k_pool(const float* __restrict__ feats,
                                              const unsigned short* __restrict__ actIdx,
                                              const int* __restrict__ cnt,
                                              float* __restrict__ poolPart) {
  int slice = blockIdx.x & (PSLICE-1);
  int pair  = blockIdx.x / PSLICE;
  int n  = cnt[pair];
  int lo = (n * slice) / PSLICE;
  int hi = (n * (slice+1)) / PSLICE;
  int tid = threadIdx.x;
  const unsigned short* ai = actIdx + (size_t)pair*P_;
  const float* fb = feats + (size_t)pair * P_ * C_ + 4*tid;
  float4 acc = make_float4(0.f, 0.f, 0.f, 0.f);
  int i = lo;
  for (; i + 8 <= hi; i += 8) {
    int r0 = ai[i+0], r1 = ai[i+1], r2 = ai[i+2], r3 = ai[i+3];
    int r4 = ai[i+4], r5 = ai[i+5], r6 = ai[i+6], r7 = ai[i+7];
    float4 v0 = *(const float4*)(fb + (size_t)r0*C_);
    float4 v1 = *(const float4*)(fb + (size_t)r1*C_);
    float4 v2 = *(const float4*)(fb + (size_t)r2*C_);
    float4 v3 = *(const float4*)(fb + (size_t)r3*C_);
    float4 v4 = *(const float4*)(fb + (size_t)r4*C_);
    float4 v5 = *(const float4*)(fb + (size_t)r5*C_);
    float4 v6 = *(const float4*)(fb + (size_t)r6*C_);
    float4 v7 = *(const float4*)(fb + (size_t)r7*C_);
    acc.x += v0.x; acc.y += v0.y; acc.z += v0.z; acc.w += v0.w;
    acc.x += v1.x; acc.y += v1.y; acc.z += v1.z; acc.w += v1.w;
    acc.x += v2.x; acc.y += v2.y; acc.z += v2.z; acc.w += v2.w;
    acc.x += v3.x; acc.y += v3.y; acc.z += v3.z; acc.w += v3.w;
    acc.x += v4.x; acc.y += v4.y; acc.z += v4.z; acc.w += v4.w;
    acc.x += v5.x; acc.y += v5.y; acc.z += v5.z; acc.w += v5.w;
    acc.x += v6.x; acc.y += v6.y; acc.z += v6.z; acc.w += v6.w;
    acc.x += v7.x; acc.y += v7.y; acc.z += v7.z; acc.w += v7.w;
  }
  for (; i < hi; i++) {
    const float4 v = *(const float4*)(fb + (size_t)ai[i]*C_);
    acc.x += v.x; acc.y += v.y; acc.z += v.z; acc.w += v.w;
  }
  *(float4*)(poolPart + ((size_t)slice*NPAIR + pair)*C_ + 4*tid) = acc;
}

// ---------------- Kernel 3: per-image token merge -> tokT [C_][64] ----------------
__global__ __launch_bounds__(256) void k_merge(const float* __restrict__ poolPart,
                                               const int* __restrict__ cnt,
                                               float* __restrict__ tokT) {
  int img = blockIdx.x;
  int tid = threadIdx.x;
  int wv = tid >> 6, ln = tid & 63;
  __shared__ float pool[MPI][C_];
  __shared__ float nrm[MPI][C_];
  __shared__ float norms[MPI];
  __shared__ float sims[MPI];
  __shared__ int seg[MPI];

  // sum the PSLICE partials (vectorized, independent loads)
  for (int idx = tid; idx < MPI*C_/4; idx += 256) {
    int m_ = idx >> 8, q = idx & 255;      // q: float4 index within row
    int pair = img*MPI + m_;
    float4 s = make_float4(0.f,0.f,0.f,0.f);
    #pragma unroll
    for (int sl = 0; sl < PSLICE; sl++) {
      float4 v = *(const float4*)(poolPart + ((size_t)sl*NPAIR + pair)*C_ + q*4);
      s.x += v.x; s.y += v.y; s.z += v.z; s.w += v.w;
    }
    float inv = 1.0f / ((float)cnt[pair] + 1e-8f);
    pool[m_][q*4+0] = s.x * inv; pool[m_][q*4+1] = s.y * inv;
    pool[m_][q*4+2] = s.z * inv; pool[m_][q*4+3] = s.w * inv;
  }
  __syncthreads();

  // norms: wave wv handles m = 2*wv, 2*wv+1
  for (int h = 0; h < 2; h++) {
    int m_ = wv*2 + h;
    float s = 0.f;
    for (int c = ln; c < C_; c += 64) { float v = pool[m_][c]; s += v*v; }
    for (int o = 32; o > 0; o >>= 1) s += __shfl_xor(s, o);
    if (ln == 0) norms[m_] = fmaxf(sqrtf(s), 1e-12f);
  }
  __syncthreads();

  for (int idx = tid; idx < MPI*C_; idx += 256) {
    int m_ = idx >> 10, c = idx & (C_-1);
    nrm[m_][c] = pool[m_][c] / norms[m_];
  }
  __syncthreads();

  // consecutive cosine sims: wave wv handles i = wv and wv+4
  for (int h = 0; h < 2; h++) {
    int i = wv + h*4;
    if (i < MPI-1) {
      float s = 0.f;
      for (int c = ln; c < C_; c += 64) s += nrm[i][c]*nrm[i+1][c];
      for (int o = 32; o > 0; o >>= 1) s += __shfl_xor(s, o);
      if (ln == 0) sims[i] = s;
    }
  }
  __syncthreads();

  if (tid == 0) {
    float v[MPI-1];
    for (int i = 0; i < MPI-1; i++) v[i] = sims[i];
    for (int i = 1; i < MPI-1; i++) {            // insertion sort desc
      float key = v[i]; int j = i-1;
      while (j >= 0 && v[j] < key) { v[j+1] = v[j]; j--; }
      v[j+1] = key;
    }
    float kth = v[RTOK-1];                        // 4th largest of 7
    int s = 0; seg[0] = 0;
    for (int i = 1; i < MPI; i++) { if (sims[i-1] < kth) s++; seg[i] = s; }
  }
  __syncthreads();

  // segment means -> transposed tokens tokT[c][img*4 + r]
  for (int idx = tid; idx < RTOK*C_; idx += 256) {
    int r = idx >> 10, c = idx & (C_-1);
    float s = 0.f; int k = 0;
    #pragma unroll
    for (int m_ = 0; m_ < MPI; m_++) {
      if (seg[m_] == r) { s += pool[m_][c]; k++; }
    }
    tokT[(size_t)c*NTOK + img*RTOK + r] = s / fmaxf((float)k, 1.0f);
  }
}

// ---------------- Skinny GEMM with depth-8 W prefetch ----------------
// 1 wave per block; wave covers 64 cols x all 64 rows. lane: mi=ln>>4 (16-row group),
// ji=ln&15 (4-col group). W loads: per-lane float4, coalesced; 8 rows in flight.
#define FMA4(ACC,AV) ACC.x=fmaf(AV,w.x,ACC.x);ACC.y=fmaf(AV,w.y,ACC.y);ACC.z=fmaf(AV,w.z,ACC.z);ACC.w=fmaf(AV,w.w,ACC.w)
__global__ __launch_bounds__(64) void k_gemm(const float* __restrict__ AT,  // [K][64]
                                             const float* __restrict__ W,   // [K][N]
                                             float* __restrict__ part,      // [S][64][N]
                                             int N, int KS) {
  int ln = threadIdx.x;
  int mi = ln >> 4;                 // 0..3
  int ji = ln & 15;                 // 0..15
  int jc = blockIdx.x*64 + ji*4;    // this thread's 4 columns
  int k0 = blockIdx.y*KS;
  float4 acc[16];
  #pragma unroll
  for (int r = 0; r < 16; r++) acc[r] = make_float4(0.f,0.f,0.f,0.f);

  const float* ap    = AT + (size_t)k0*NTOK + mi*16;
  const float* wbase = W  + (size_t)k0*N + jc;
  const float* wp    = wbase;
  float4 wbuf[8];
  #pragma unroll
  for (int kk = 0; kk < 8; kk++) wbuf[kk] = *(const float4*)(wp + (size_t)kk*N);
  wp += 8*(size_t)N;

  for (int k8 = 0; k8 < KS; k8 += 8) {
    bool more = (k8 + 8) < KS;
    const float* pre = more ? wp : wbase;    // last chunk: dummy in-bounds prefetch
    #pragma unroll
    for (int kk = 0; kk < 8; kk++) {
      float4 a0 = *(const float4*)(ap);
      float4 a1 = *(const float4*)(ap+4);
      float4 a2 = *(const float4*)(ap+8);
      float4 a3 = *(const float4*)(ap+12);
      ap += NTOK;
      float4 w = wbuf[kk];
      FMA4(acc[0], a0.x); FMA4(acc[1], a0.y); FMA4(acc[2], a0.z); FMA4(acc[3], a0.w);
      FMA4(acc[4], a1.x); FMA4(acc[5], a1.y); FMA4(acc[6], a1.z); FMA4(acc[7], a1.w);
      FMA4(acc[8], a2.x); FMA4(acc[9], a2.y); FMA4(acc[10],a2.z); FMA4(acc[11],a2.w);
      FMA4(acc[12],a3.x); FMA4(acc[13],a3.y); FMA4(acc[14],a3.z); FMA4(acc[15],a3.w);
      wbuf[kk] = *(const float4*)(pre + (size_t)kk*N);   // prefetch next chunk
    }
    wp += 8*(size_t)N;
  }
  #pragma unroll
  for (int q = 0; q < 4; q++)
    #pragma unroll
    for (int r = 0; r < 4; r++) {
      int row = mi*16 + q*4 + r;
      *(float4*)(part + ((size_t)blockIdx.y*NTOK + row)*N + jc) = acc[q*4+r];
    }
}

// ---------------- reduce1: sum S1 k-slices + b1, exact GELU, write hT [CH_][64] ----------------
__global__ __launch_bounds__(256) void k_reduce1(const float* __restrict__ part, // [S1][64][CH_]
                                                 const float* __restrict__ b1,
                                                 float* __restrict__ hT) {
  __shared__ float tile[64][65];
  int j0 = blockIdx.x * 64;
  int tid = threadIdx.x;
  // 64 rows x 16 float4s per block
  for (int i = tid; i < 64*16; i += 256) {
    int m = i >> 4, jq = i & 15;
    float4 s = make_float4(0.f,0.f,0.f,0.f);
    #pragma unroll
    for (int ss = 0; ss < S1; ss++) {
      float4 v = *(const float4*)(part + ((size_t)ss*NTOK + m)*CH_ + j0 + jq*4);
      s.x += v.x; s.y += v.y; s.z += v.z; s.w += v.w;
    }
    float4 b = *(const float4*)(b1 + j0 + jq*4);
    s.x += b.x; s.y += b.y; s.z += b.z; s.w += b.w;
    tile[jq*4+0][m] = 0.5f*s.x*(1.0f + erff(s.x*0.70710678118654752f));
    tile[jq*4+1][m] = 0.5f*s.y*(1.0f + erff(s.y*0.70710678118654752f));
    tile[jq*4+2][m] = 0.5f*s.z*(1.0f + erff(s.z*0.70710678118654752f));
    tile[jq*4+3][m] = 0.5f*s.w*(1.0f + erff(s.w*0.70710678118654752f));
  }
  __syncthreads();
  for (int i = tid; i < 64*64; i += 256) {
    int jj = i >> 6, m = i & 63;
    hT[(size_t)(j0 + jj)*NTOK + m] = tile[jj][m];
  }
}

// ---------------- reduce2: sum S2 k-slices + b2 -> d_out [64][CH_] (float4) ----------------
__global__ __launch_bounds__(256) void k_reduce2(const float4* __restrict__ part, // [S2][64][CH_/4]
                                                 const float4* __restrict__ b2,
                                                 float4* __restrict__ out) {
  int idx = blockIdx.x*256 + threadIdx.x;   // over 64*1024 float4s
  float4 s = make_float4(0.f,0.f,0.f,0.f);
  #pragma unroll
  for (int ss = 0; ss < S2; ss++) {
    float4 v = part[(size_t)ss*(NTOK*CH_/4) + idx];
    s.x += v.x; s.y += v.y; s.z += v.z; s.w += v.w;
  }
  float4 b = b2[idx & (CH_/4 - 1)];
  s.x += b.x; s.y += b.y; s.z += b.z; s.w += b.w;
  out[idx] = s;
}

extern "C" void kernel_launch(void* const* d_in, const int* in_sizes, int n_in,
                              void* d_out, int out_size, void* d_ws, size_t ws_size,
                              hipStream_t stream) {
  (void)in_sizes; (void)n_in; (void)out_size; (void)ws_size;
  const float* feats = (const float*)d_in[0];
  const float* masks = (const float*)d_in[1];
  const float* W1    = (const float*)d_in[2];
  const float* b1    = (const float*)d_in[3];
  const float* W2    = (const float*)d_in[4];
  const float* b2    = (const float*)d_in[5];
  float* out = (float*)d_out;
  char* ws = (char*)d_ws;

  // workspace layout (bytes, all 16B-aligned)
  unsigned short* actIdx = (unsigned short*)(ws + 0);        // 128*576*2      = 147456
  int*   cnt      = (int*)  (ws + 147456);                   // 128*4 (pad)    = 512
  float* poolPart = (float*)(ws + 147968);                   // 8*128*1024*4   = 4194304
  float* tokT     = (float*)(ws + 4342272);                  // 1024*64*4      = 262144
  float* g1part   = (float*)(ws + 4604416);                  // 16*64*4096*4   = 16777216
  float* hT       = (float*)(ws + 21381632);                 // 4096*64*4      = 1048576
  float* g2part   = (float*)(ws + 22430208);                 // 16*64*4096*4   = 16777216
  // total ~39.2 MB

  k_mask <<<NPAIR, 512, 0, stream>>>(masks, actIdx, cnt);
  k_pool <<<NPAIR*PSLICE, 256, 0, stream>>>(feats, actIdx, cnt, poolPart);
  k_merge<<<NIMG, 256, 0, stream>>>(poolPart, cnt, tokT);
  // GEMM1: [64,1024] @ [1024,4096], S1 k-slices of 64
  k_gemm <<<dim3(CH_/64, S1), 64, 0, stream>>>(tokT, W1, g1part, CH_, C_/S1);
  k_reduce1<<<CH_/64, 256, 0, stream>>>(g1part, b1, hT);
  // GEMM2: [64,4096] @ [4096,4096], S2 k-slices of 256
  k_gemm <<<dim3(CH_/64, S2), 64, 0, stream>>>(hT, W2, g2part, CH_, CH_/S2);
  k_reduce2<<<(NTOK*CH_/4)/256, 256, 0, stream>>>((const float4*)g2part, (const float4*)b2, (float4*)out);
}